// Round 8
// baseline (928.336 us; speedup 1.0000x reference)
//
#include <hip/hip_runtime.h>
#include <hip/hip_cooperative_groups.h>

namespace cg = cooperative_groups;

#define NN 50000
#define EE 800000
#define DD 128
#define BN_EPS 1e-5f
#define SCAN_B 196      // ceil(50000/256)
#define XCONV_B 3125    // N*D/8/256
#define EDGE_B 3125     // EE/256
#define BIN_BLOCKS 200
#define BIN_EDGES 4000  // per virtual block; 200*4000 == EE
#define AGG_B 12500     // NN/4
#define GEMM_B 782      // ceil(NN/64)
#define NREP 32         // BN-stat replica count

typedef __attribute__((ext_vector_type(8))) short bf16x8;
typedef __attribute__((ext_vector_type(4))) float f32x4;
typedef __attribute__((ext_vector_type(8))) unsigned short u16x8;

__device__ inline unsigned short f2bf(float f) {  // RNE fp32 -> bf16
  unsigned int u = __float_as_uint(f);
  u = (u + 0x7fffu + ((u >> 16) & 1u)) >> 16;
  return (unsigned short)u;
}
__device__ inline float bf2f(unsigned short b) {
  return __uint_as_float(((unsigned int)b) << 16);
}

// ---------------------------------------------------------------------------
// Single cooperative mega-kernel. Phases separated by grid.sync():
//  P0 prep | P1 hist | P2 scanA | P3 scanC | P4 bin | P5 place2 | P6 agg |
//  P7 gemm1 | P8 gemm2 | P9 bnstats2 | P10 bnrelu
// Memory plan identical to R7 (d_out scratch dead until P10 writes d_out):
//  d_out: ints[offs|cnt|cursor|sc|partial|bcur] | xb@4.0M | pairs@16.8M |
//         W1b@23.28M | W2b@23.36M | reps@23.5M (64KB)
//  d_ws:  h0b (->h2b) | h1b | stats(scale2,shift2)@25.6M
// ---------------------------------------------------------------------------
__global__ __launch_bounds__(256, 4) void k_mega(
    const float* __restrict__ x, const int* __restrict__ ei,
    const float* __restrict__ eps, const float* __restrict__ W1,
    const float* __restrict__ b1, const float* __restrict__ g1,
    const float* __restrict__ be1, const float* __restrict__ W2,
    const float* __restrict__ b2, const float* __restrict__ g2,
    const float* __restrict__ be2, float* __restrict__ out,
    unsigned short* __restrict__ ws) {
  cg::grid_group grid = cg::this_grid();
  const int nB = gridDim.x;
  const int bx = blockIdx.x;
  const int t = threadIdx.x;

  __shared__ __align__(16) char smem[4096];
  int* si = (int*)smem;

  // --- scratch pointers (inside d_out) ---
  int* scr = (int*)out;
  int* offs = scr;               // NN+1
  int* cnt = scr + 50008;        // NN
  int* cursor = scr + 100016;    // NN
  int* sc = scr + 150024;        // EE
  int* partial = scr + 950024;   // SCAN_B
  int* bcur = scr + 950240;      // SCAN_B(+pad)
  const int* rows = ei;
  const int* cols = ei + EE;
  unsigned short* xb = (unsigned short*)out + 2000000;    // byte 4.0M
  int2* pairs = (int2*)((char*)out + 16800000);           // byte 16.8M
  unsigned short* W1b = (unsigned short*)out + 11640000;  // byte 23.28M
  unsigned short* W2b = (unsigned short*)out + 11680000;  // byte 23.36M
  float* reps = (float*)out + 5875000;                    // byte 23.5M
  float* sum1r = reps;
  float* sumsq1r = reps + NREP * DD;
  float* sum2r = reps + 2 * NREP * DD;
  float* sumsq2r = reps + 3 * NREP * DD;

  unsigned short* h0b = ws;                        // region A
  unsigned short* h1b = ws + (size_t)NN * DD;      // region B
  unsigned short* h2b = ws;                        // region A (reuse)
  float* stats = (float*)(ws + (size_t)2 * NN * DD);
  float* scale2 = stats + 0;
  float* shift2 = stats + 128;

  // ===== P0: prep — x->bf16, W1/W2->bf16, zero cnt + replicas =====
  for (int vb = bx; vb < XCONV_B + 32; vb += nB) {
    if (vb < XCONV_B) {
      const int gid = vb * 256 + t;
      const float4 v0 = ((const float4*)x)[gid * 2];
      const float4 v1 = ((const float4*)x)[gid * 2 + 1];
      ushort4 o0, o1;
      o0.x = f2bf(v0.x); o0.y = f2bf(v0.y); o0.z = f2bf(v0.z); o0.w = f2bf(v0.w);
      o1.x = f2bf(v1.x); o1.y = f2bf(v1.y); o1.z = f2bf(v1.z); o1.w = f2bf(v1.w);
      ((ushort4*)xb)[gid * 2] = o0;
      ((ushort4*)xb)[gid * 2 + 1] = o1;
      if (gid < NN) cnt[gid] = 0;
      if (gid < 4 * NREP * DD) reps[gid] = 0.0f;
    } else if (vb < XCONV_B + 16) {
      const int gid = (vb - XCONV_B) * 256 + t;
      const float4 v = ((const float4*)W1)[gid];
      ushort4 o;
      o.x = f2bf(v.x); o.y = f2bf(v.y); o.z = f2bf(v.z); o.w = f2bf(v.w);
      ((ushort4*)W1b)[gid] = o;
    } else {
      const int gid = (vb - XCONV_B - 16) * 256 + t;
      const float4 v = ((const float4*)W2)[gid];
      ushort4 o;
      o.x = f2bf(v.x); o.y = f2bf(v.y); o.z = f2bf(v.z); o.w = f2bf(v.w);
      ((ushort4*)W2b)[gid] = o;
    }
  }
  grid.sync();

  // ===== P1: in-degree histogram =====
  for (int vb = bx; vb < EDGE_B; vb += nB) {
    atomicAdd(&cnt[rows[vb * 256 + t]], 1);
  }
  grid.sync();

  // ===== P2: per-chunk reduce -> partial =====
  for (int vb = bx; vb < SCAN_B; vb += nB) {
    __syncthreads();
    const int i = vb * 256 + t;
    si[t] = (i < NN) ? cnt[i] : 0;
    __syncthreads();
#pragma unroll
    for (int off = 128; off > 0; off >>= 1) {
      if (t < off) si[t] += si[t + off];
      __syncthreads();
    }
    if (t == 0) partial[vb] = si[0];
  }
  grid.sync();

  // ===== P3: per-chunk scan -> offs, cursor, bcur =====
  for (int vb = bx; vb < SCAN_B; vb += nB) {
    __syncthreads();
    si[t] = (t < SCAN_B && t < vb) ? partial[t] : 0;
    __syncthreads();
#pragma unroll
    for (int off = 128; off > 0; off >>= 1) {
      if (t < off) si[t] += si[t + off];
      __syncthreads();
    }
    if (t == 0) si[256] = si[0];
    __syncthreads();
    const int base = si[256];
    __syncthreads();
    const int i = vb * 256 + t;
    const int own = (i < NN) ? cnt[i] : 0;
    si[t] = own;
    __syncthreads();
#pragma unroll
    for (int off = 1; off < 256; off <<= 1) {
      const int v = (t >= off) ? si[t - off] : 0;
      __syncthreads();
      si[t] += v;
      __syncthreads();
    }
    if (i < NN) {
      const int o = base + si[t] - own;
      offs[i] = o;
      cursor[i] = o;
    }
    if (t == 0) bcur[vb] = base;
    if (vb == 0 && t == 0) offs[NN] = EE;
  }
  grid.sync();

  // ===== P4: bin edges into bucket-contiguous (row,col) pairs =====
  {
    int* hist = si;
    int* lbase = si + 256;
    for (int vb = bx; vb < BIN_BLOCKS; vb += nB) {
      __syncthreads();
      hist[t] = 0;
      __syncthreads();
      const int e0 = vb * BIN_EDGES;
      int er[16], ec[16];
#pragma unroll
      for (int i = 0; i < 16; ++i) {
        const int idx = t + i * 256;
        if (idx < BIN_EDGES) {
          er[i] = rows[e0 + idx];
          ec[i] = cols[e0 + idx];
          atomicAdd(&hist[er[i] >> 8], 1);
        }
      }
      __syncthreads();
      const int c = hist[t];
      __syncthreads();
      if (c > 0) lbase[t] = atomicAdd(&bcur[t], c);
      hist[t] = 0;  // reuse as local placement cursor
      __syncthreads();
#pragma unroll
      for (int i = 0; i < 16; ++i) {
        const int idx = t + i * 256;
        if (idx < BIN_EDGES) {
          const int bk = er[i] >> 8;
          const int lp = atomicAdd(&hist[bk], 1);
          pairs[lbase[bk] + lp] = make_int2(er[i], ec[i]);
        }
      }
    }
  }
  grid.sync();

  // ===== P5: final placement from bucket-ordered pairs =====
  for (int vb = bx; vb < EDGE_B; vb += nB) {
    const int2 p = pairs[vb * 256 + t];
    const int pos = atomicAdd(&cursor[p.x], 1);
    sc[pos] = p.y;
  }
  grid.sync();

  // ===== P6: gather aggregation (one wave per dest row) =====
  {
    const int wv = t >> 6;
    const int lane = t & 63;
    const int sub = lane >> 4;
    const int l16 = lane & 15;
    const float s = 1.0f + eps[0];
    for (int vb = bx; vb < AGG_B; vb += nB) {
      const int v = vb * 4 + wv;
      const int beg = offs[v];
      const int end = offs[v + 1];
      float acc[8];
      if (sub == 0) {
        const u16x8 a = *(const u16x8*)(xb + (size_t)v * DD + l16 * 8);
#pragma unroll
        for (int j = 0; j < 8; ++j) acc[j] = s * bf2f(a[j]);
      } else {
#pragma unroll
        for (int j = 0; j < 8; ++j) acc[j] = 0.f;
      }
      int i = beg + sub;
      for (; i + 4 < end; i += 8) {
        const int u0 = sc[i];
        const int u1 = sc[i + 4];
        const u16x8 a = *(const u16x8*)(xb + (size_t)u0 * DD + l16 * 8);
        const u16x8 b = *(const u16x8*)(xb + (size_t)u1 * DD + l16 * 8);
#pragma unroll
        for (int j = 0; j < 8; ++j) acc[j] += bf2f(a[j]) + bf2f(b[j]);
      }
      if (i < end) {
        const int u = sc[i];
        const u16x8 a = *(const u16x8*)(xb + (size_t)u * DD + l16 * 8);
#pragma unroll
        for (int j = 0; j < 8; ++j) acc[j] += bf2f(a[j]);
      }
#pragma unroll
      for (int j = 0; j < 8; ++j) {
        acc[j] += __shfl_xor(acc[j], 16);
        acc[j] += __shfl_xor(acc[j], 32);
      }
      if (sub == 0) {
        u16x8 o;
#pragma unroll
        for (int j = 0; j < 8; ++j) o[j] = f2bf(acc[j]);
        *(u16x8*)(h0b + (size_t)v * DD + l16 * 8) = o;
      }
    }
  }
  grid.sync();

  // ===== P7: GEMM1 (h1b = bf16(h0b @ W1^T + b1)); BN1 replica stats =====
  {
    float* bsum = (float*)smem;
    float* bsq = bsum + DD;
    const int wv = t >> 6;
    const int lane = t & 63;
    const int quad = lane >> 4;
    const int l16 = lane & 15;
    for (int vb = bx; vb < GEMM_B; vb += nB) {
      __syncthreads();
      if (t < DD) { bsum[t] = 0.f; bsq[t] = 0.f; }
      __syncthreads();
      const int rowbase = vb * 64 + wv * 16 + l16;
      const int arow = rowbase < NN ? rowbase : NN - 1;
      const unsigned short* aptr = h0b + (size_t)arow * DD + quad * 8;
      f32x4 acc[8];
#pragma unroll
      for (int n = 0; n < 8; ++n) acc[n] = (f32x4){0.f, 0.f, 0.f, 0.f};
#pragma unroll
      for (int kk = 0; kk < 4; ++kk) {
        const bf16x8 af = *(const bf16x8*)(aptr + kk * 32);
#pragma unroll
        for (int n = 0; n < 8; ++n) {
          const bf16x8 bf = *(const bf16x8*)(W1b + (size_t)(n * 16 + l16) * DD +
                                             quad * 8 + kk * 32);
          acc[n] = __builtin_amdgcn_mfma_f32_16x16x32_bf16(af, bf, acc[n], 0, 0, 0);
        }
      }
      const int orow0 = vb * 64 + wv * 16 + quad * 4;
#pragma unroll
      for (int n = 0; n < 8; ++n) {
        const int col = n * 16 + l16;
        const float bv = b1[col];
        float sv = 0.f, qv = 0.f;
#pragma unroll
        for (int r = 0; r < 4; ++r) {
          const int row = orow0 + r;
          if (row < NN) {
            const float o = acc[n][r] + bv;
            h1b[(size_t)row * DD + col] = f2bf(o);
            sv += o; qv += o * o;
          }
        }
        sv += __shfl_xor(sv, 16); qv += __shfl_xor(qv, 16);
        sv += __shfl_xor(sv, 32); qv += __shfl_xor(qv, 32);
        if (quad == 0) { atomicAdd(&bsum[col], sv); atomicAdd(&bsq[col], qv); }
      }
      __syncthreads();
      if (t < DD) {
        const int rep = (vb & (NREP - 1)) * DD;
        atomicAdd(&sum1r[rep + t], bsum[t]);
        atomicAdd(&sumsq1r[rep + t], bsq[t]);
      }
    }
  }
  grid.sync();

  // ===== P8: GEMM2 (A = relu(BN1(h1b)) on the fly) -> h2b; BN2 replicas =====
  {
    float* lsc = (float*)smem;          // 128
    float* lsh = lsc + DD;              // 128
    float* bsum = lsc + 2 * DD;         // 128
    float* bsq = lsc + 3 * DD;          // 128
    const int wv = t >> 6;
    const int lane = t & 63;
    const int quad = lane >> 4;
    const int l16 = lane & 15;
    for (int vb = bx; vb < GEMM_B; vb += nB) {
      __syncthreads();
      if (t < DD) {
        float sm = 0.f, qm = 0.f;
#pragma unroll
        for (int r = 0; r < NREP; ++r) {
          sm += sum1r[r * DD + t];
          qm += sumsq1r[r * DD + t];
        }
        const float inv_n = 1.0f / (float)NN;
        const float mean = sm * inv_n;
        const float var = qm * inv_n - mean * mean;
        const float s = g1[t] * rsqrtf(var + BN_EPS);
        lsc[t] = s;
        lsh[t] = be1[t] - mean * s;
        bsum[t] = 0.f;
        bsq[t] = 0.f;
      }
      __syncthreads();
      const int rowbase = vb * 64 + wv * 16 + l16;
      const int arow = rowbase < NN ? rowbase : NN - 1;
      const unsigned short* aptr = h1b + (size_t)arow * DD + quad * 8;
      f32x4 acc[8];
#pragma unroll
      for (int n = 0; n < 8; ++n) acc[n] = (f32x4){0.f, 0.f, 0.f, 0.f};
#pragma unroll
      for (int kk = 0; kk < 4; ++kk) {
        const int kbase = kk * 32 + quad * 8;
        const u16x8 a = *(const u16x8*)(aptr + kk * 32);
        const float4 s0 = *(const float4*)&lsc[kbase];
        const float4 s1 = *(const float4*)&lsc[kbase + 4];
        const float4 h0 = *(const float4*)&lsh[kbase];
        const float4 h1 = *(const float4*)&lsh[kbase + 4];
        bf16x8 af;
        af[0] = (short)f2bf(fmaxf(fmaf(s0.x, bf2f(a[0]), h0.x), 0.f));
        af[1] = (short)f2bf(fmaxf(fmaf(s0.y, bf2f(a[1]), h0.y), 0.f));
        af[2] = (short)f2bf(fmaxf(fmaf(s0.z, bf2f(a[2]), h0.z), 0.f));
        af[3] = (short)f2bf(fmaxf(fmaf(s0.w, bf2f(a[3]), h0.w), 0.f));
        af[4] = (short)f2bf(fmaxf(fmaf(s1.x, bf2f(a[4]), h1.x), 0.f));
        af[5] = (short)f2bf(fmaxf(fmaf(s1.y, bf2f(a[5]), h1.y), 0.f));
        af[6] = (short)f2bf(fmaxf(fmaf(s1.z, bf2f(a[6]), h1.z), 0.f));
        af[7] = (short)f2bf(fmaxf(fmaf(s1.w, bf2f(a[7]), h1.w), 0.f));
#pragma unroll
        for (int n = 0; n < 8; ++n) {
          const bf16x8 bf =
              *(const bf16x8*)(W2b + (size_t)(n * 16 + l16) * DD + kbase);
          acc[n] = __builtin_amdgcn_mfma_f32_16x16x32_bf16(af, bf, acc[n], 0, 0, 0);
        }
      }
      const int orow0 = vb * 64 + wv * 16 + quad * 4;
#pragma unroll
      for (int n = 0; n < 8; ++n) {
        const int col = n * 16 + l16;
        const float bv = b2[col];
        float sv = 0.f, qv = 0.f;
#pragma unroll
        for (int r = 0; r < 4; ++r) {
          const int row = orow0 + r;
          if (row < NN) {
            const float o = acc[n][r] + bv;
            h2b[(size_t)row * DD + col] = f2bf(o);
            sv += o; qv += o * o;
          }
        }
        sv += __shfl_xor(sv, 16); qv += __shfl_xor(qv, 16);
        sv += __shfl_xor(sv, 32); qv += __shfl_xor(qv, 32);
        if (quad == 0) { atomicAdd(&bsum[col], sv); atomicAdd(&bsq[col], qv); }
      }
      __syncthreads();
      if (t < DD) {
        const int rep = (vb & (NREP - 1)) * DD;
        atomicAdd(&sum2r[rep + t], bsum[t]);
        atomicAdd(&sumsq2r[rep + t], bsq[t]);
      }
    }
  }
  grid.sync();

  // ===== P9: collapse BN2 replicas -> scale2/shift2 in d_ws =====
  if (bx == 0 && t < DD) {
    float sm = 0.f, qm = 0.f;
#pragma unroll
    for (int r = 0; r < NREP; ++r) {
      sm += sum2r[r * DD + t];
      qm += sumsq2r[r * DD + t];
    }
    const float inv_n = 1.0f / (float)NN;
    const float mean = sm * inv_n;
    const float var = qm * inv_n - mean * mean;
    const float s = g2[t] * rsqrtf(var + BN_EPS);
    scale2[t] = s;
    shift2[t] = be2[t] - mean * s;
  }
  grid.sync();

  // ===== P10: final BN2 + ReLU -> fp32 out (overwrites d_out) =====
  {
    float* lsc = (float*)smem;
    float* lsh = lsc + DD;
    __syncthreads();
    if (t < DD) {
      lsc[t] = scale2[t];
      lsh[t] = shift2[t];
    }
    __syncthreads();
    for (int vb = bx; vb < XCONV_B; vb += nB) {
      const int gid = vb * 256 + t;
      const int c = (gid & 15) * 8;
      const u16x8 a = ((const u16x8*)h2b)[gid];
      const float4 sc0 = *(const float4*)&lsc[c];
      const float4 sc1 = *(const float4*)&lsc[c + 4];
      const float4 sh0 = *(const float4*)&lsh[c];
      const float4 sh1 = *(const float4*)&lsh[c + 4];
      float4 o0, o1;
      o0.x = fmaxf(fmaf(sc0.x, bf2f(a[0]), sh0.x), 0.f);
      o0.y = fmaxf(fmaf(sc0.y, bf2f(a[1]), sh0.y), 0.f);
      o0.z = fmaxf(fmaf(sc0.z, bf2f(a[2]), sh0.z), 0.f);
      o0.w = fmaxf(fmaf(sc0.w, bf2f(a[3]), sh0.w), 0.f);
      o1.x = fmaxf(fmaf(sc1.x, bf2f(a[4]), sh1.x), 0.f);
      o1.y = fmaxf(fmaf(sc1.y, bf2f(a[5]), sh1.y), 0.f);
      o1.z = fmaxf(fmaf(sc1.z, bf2f(a[6]), sh1.z), 0.f);
      o1.w = fmaxf(fmaf(sc1.w, bf2f(a[7]), sh1.w), 0.f);
      ((float4*)out)[gid * 2] = o0;
      ((float4*)out)[gid * 2 + 1] = o1;
    }
  }
}

// ---------------------------------------------------------------------------
extern "C" void kernel_launch(void* const* d_in, const int* in_sizes, int n_in,
                              void* d_out, int out_size, void* d_ws, size_t ws_size,
                              hipStream_t stream) {
  const float* x = (const float*)d_in[0];
  const int* ei = (const int*)d_in[1];
  const float* eps = (const float*)d_in[2];
  const float* W1 = (const float*)d_in[3];
  const float* b1 = (const float*)d_in[4];
  const float* g1 = (const float*)d_in[5];
  const float* be1 = (const float*)d_in[6];
  const float* W2 = (const float*)d_in[7];
  const float* b2 = (const float*)d_in[8];
  const float* g2 = (const float*)d_in[9];
  const float* be2 = (const float*)d_in[10];
  float* out = (float*)d_out;
  unsigned short* ws = (unsigned short*)d_ws;

  // co-resident grid size (expected 4 blocks/CU * 256 CUs = 1024)
  int perCU = 0;
  if (hipOccupancyMaxActiveBlocksPerMultiprocessor(&perCU, (const void*)k_mega,
                                                   256, 0) != hipSuccess ||
      perCU < 1) {
    perCU = 2;  // conservative fallback, guaranteed co-resident
  }
  if (perCU > 8) perCU = 8;
  int gblocks = perCU * 256;
  if (gblocks > 2048) gblocks = 2048;

  void* args[] = {&x, &ei, &eps, &W1, &b1, &g1, &be1,
                  &W2, &b2, &g2, &be2, &out, &ws};
  hipLaunchCooperativeKernel((const void*)k_mega, dim3(gblocks), dim3(256),
                             args, 0, stream);
}

// Round 9
// 214.122 us; speedup vs baseline: 4.3356x; 4.3356x over previous
//
#include <hip/hip_runtime.h>

#define NN 50000
#define EE 800000
#define DD 128
#define BN_EPS 1e-5f
#define XCONV_B 3125    // N*D/8/256
#define BIN_BLOCKS 200
#define BIN_EDGES 4000  // per block; 200*4000 == EE
#define NBUCK 782       // ceil(NN/64): 64-row buckets
#define BCAP 2048       // bucket capacity (mean 1023, Poisson tail ~e^-300)
#define NREP 32         // BN-stat replica count
#define GEMM_B 782      // ceil(NN/64)

typedef __attribute__((ext_vector_type(8))) short bf16x8;
typedef __attribute__((ext_vector_type(4))) float f32x4;
typedef __attribute__((ext_vector_type(8))) unsigned short u16x8;

__device__ inline unsigned short f2bf(float f) {  // RNE fp32 -> bf16
  unsigned int u = __float_as_uint(f);
  u = (u + 0x7fffu + ((u >> 16) & 1u)) >> 16;
  return (unsigned short)u;
}
__device__ inline float bf2f(unsigned short b) {
  return __uint_as_float(((unsigned int)b) << 16);
}

// ---------------------------------------------------------------------------
// Memory plan (byte offsets into d_out, 25.6MB; all scratch dead before the
// final k_bnrelu overwrites d_out with the fp32 result):
//   [0, +3128B)     bcur[NBUCK] bucket cursors
//   [4.0M, 16.8M)   xb  = bf16(x)                  (dies after k_aggb)
//   [16.8M, 23.2M)  bbuf = u32[NBUCK*BCAP] packed (row&63)<<16|col
//   [23.28M,+32KB)  W1b; [23.36M,+32KB) W2b
//   [23.5M, +64KB)  reps: sum1[NREP][128] | sumsq1 | sum2 | sumsq2
// d_ws (25.6MB + 4KB): region A h0b->h2b | region B h1b |
//   stats at +25.6M: scale2[128] | shift2[128]
// 7 dispatches (was 11).  NOTE (R8 lesson): cooperative grid.sync() costs
// ~100us/sync on MI355X (device-scope L2 flush across XCDs) — never again.
// ---------------------------------------------------------------------------

// K0: fused prep — x->bf16, W1->bf16, W2->bf16, zero bcur + stat replicas
__global__ __launch_bounds__(256) void k_prep(const float* __restrict__ x,
                                              const float* __restrict__ W1,
                                              const float* __restrict__ W2,
                                              unsigned short* __restrict__ xb,
                                              unsigned short* __restrict__ W1b,
                                              unsigned short* __restrict__ W2b,
                                              int* __restrict__ bcur,
                                              float* __restrict__ reps) {
  const int b = blockIdx.x;
  const int t = threadIdx.x;
  if (b < XCONV_B) {
    const int gid = b * 256 + t;
    const float4 v0 = ((const float4*)x)[gid * 2];
    const float4 v1 = ((const float4*)x)[gid * 2 + 1];
    ushort4 o0, o1;
    o0.x = f2bf(v0.x); o0.y = f2bf(v0.y); o0.z = f2bf(v0.z); o0.w = f2bf(v0.w);
    o1.x = f2bf(v1.x); o1.y = f2bf(v1.y); o1.z = f2bf(v1.z); o1.w = f2bf(v1.w);
    ((ushort4*)xb)[gid * 2] = o0;
    ((ushort4*)xb)[gid * 2 + 1] = o1;
    if (gid < NBUCK) bcur[gid] = 0;
    if (gid < 4 * NREP * DD) reps[gid] = 0.0f;  // 16384 floats
  } else if (b < XCONV_B + 16) {
    const int gid = (b - XCONV_B) * 256 + t;
    const float4 v = ((const float4*)W1)[gid];
    ushort4 o;
    o.x = f2bf(v.x); o.y = f2bf(v.y); o.z = f2bf(v.z); o.w = f2bf(v.w);
    ((ushort4*)W1b)[gid] = o;
  } else {
    const int gid = (b - XCONV_B - 16) * 256 + t;
    const float4 v = ((const float4*)W2)[gid];
    ushort4 o;
    o.x = f2bf(v.x); o.y = f2bf(v.y); o.z = f2bf(v.z); o.w = f2bf(v.w);
    ((ushort4*)W2b)[gid] = o;
  }
}

// K1: bin edges into fixed-capacity 64-row buckets. Per block: LDS histogram
// over buckets -> one global range reservation per bucket -> packed writes
// into block-private contiguous segments (no cross-block line sharing).
__global__ __launch_bounds__(256) void k_bin0(const int* __restrict__ rows,
                                              const int* __restrict__ cols,
                                              int* __restrict__ bcur,
                                              unsigned int* __restrict__ bbuf) {
  __shared__ int hist[NBUCK];
  __shared__ int lbase[NBUCK];
  const int t = threadIdx.x;
  for (int i = t; i < NBUCK; i += 256) hist[i] = 0;
  __syncthreads();
  const int e0 = blockIdx.x * BIN_EDGES;
  int er[16], ec[16];
#pragma unroll
  for (int i = 0; i < 16; ++i) {
    const int idx = t + i * 256;
    if (idx < BIN_EDGES) {
      er[i] = rows[e0 + idx];
      ec[i] = cols[e0 + idx];
      atomicAdd(&hist[er[i] >> 6], 1);
    }
  }
  __syncthreads();
  for (int i = t; i < NBUCK; i += 256) {
    const int c = hist[i];
    lbase[i] = (c > 0) ? atomicAdd(&bcur[i], c) : 0;
    hist[i] = 0;  // reuse as local placement cursor
  }
  __syncthreads();
#pragma unroll
  for (int i = 0; i < 16; ++i) {
    const int idx = t + i * 256;
    if (idx < BIN_EDGES) {
      const int bk = er[i] >> 6;
      const int lp = lbase[bk] + atomicAdd(&hist[bk], 1);
      if (lp < BCAP)  // statistically impossible overflow; memory-safety clamp
        bbuf[(size_t)bk * BCAP + lp] =
            ((unsigned)(er[i] & 63) << 16) | (unsigned)ec[i];
    }
  }
}

// K2: per-bucket LDS counting sort + gather aggregation.
// Block = bucket (64 rows). Sort bucket's edges by row in LDS, then one wave
// per row (4 neighbor-slots x 16 lanes) gathers xb rows and reduces.
__global__ __launch_bounds__(256) void k_aggb(const unsigned short* __restrict__ xb,
                                              const float* __restrict__ eps,
                                              const int* __restrict__ bcnt,
                                              const unsigned int* __restrict__ bbuf,
                                              unsigned short* __restrict__ h0b) {
  __shared__ unsigned short scols[BCAP];  // 4KB: col ids sorted by row
  __shared__ int rcnt[64];
  __shared__ int roff[65];
  __shared__ int sscan[256];
  const int t = threadIdx.x;
  const int bk = blockIdx.x;
  int n = bcnt[bk];
  n = n < BCAP ? n : BCAP;
  if (t < 64) rcnt[t] = 0;
  __syncthreads();
  // load entries (register stash) + per-row count
  unsigned int ent[8];
  int nl = 0;
  for (int i = t; i < n; i += 256) {
    const unsigned int e = bbuf[(size_t)bk * BCAP + i];
    ent[nl++] = e;
    atomicAdd(&rcnt[e >> 16], 1);
  }
  __syncthreads();
  // exclusive scan of the 64 row-counts (block-wide Hillis-Steele)
  sscan[t] = (t < 64) ? rcnt[t] : 0;
  __syncthreads();
#pragma unroll
  for (int off = 1; off < 64; off <<= 1) {
    const int v = (t >= off) ? sscan[t - off] : 0;
    __syncthreads();
    sscan[t] += v;
    __syncthreads();
  }
  if (t < 64) {
    roff[t] = sscan[t] - rcnt[t];
    rcnt[t] = 0;  // reuse as placement cursor
  }
  if (t == 63) roff[64] = sscan[63];
  __syncthreads();
  // place col ids into row-sorted LDS list
  for (int i = 0; i < nl; ++i) {
    const int r = ent[i] >> 16;
    const int pos = roff[r] + atomicAdd(&rcnt[r], 1);
    scols[pos] = (unsigned short)(ent[i] & 0xffffu);
  }
  __syncthreads();
  // aggregate: wave wv handles rows wv, wv+4, ...
  const int wv = t >> 6;
  const int lane = t & 63;
  const int sub = lane >> 4;
  const int l16 = lane & 15;
  const float s = 1.0f + eps[0];
  for (int r = wv; r < 64; r += 4) {
    const int v = bk * 64 + r;
    if (v >= NN) continue;
    const int beg = roff[r];
    const int end = roff[r + 1];
    float acc[8];
    if (sub == 0) {
      const u16x8 a = *(const u16x8*)(xb + (size_t)v * DD + l16 * 8);
#pragma unroll
      for (int j = 0; j < 8; ++j) acc[j] = s * bf2f(a[j]);
    } else {
#pragma unroll
      for (int j = 0; j < 8; ++j) acc[j] = 0.f;
    }
    int i = beg + sub;
    for (; i + 4 < end; i += 8) {
      const int u0 = scols[i];
      const int u1 = scols[i + 4];
      const u16x8 a = *(const u16x8*)(xb + (size_t)u0 * DD + l16 * 8);
      const u16x8 b = *(const u16x8*)(xb + (size_t)u1 * DD + l16 * 8);
#pragma unroll
      for (int j = 0; j < 8; ++j) acc[j] += bf2f(a[j]) + bf2f(b[j]);
    }
    if (i < end) {
      const int u = scols[i];
      const u16x8 a = *(const u16x8*)(xb + (size_t)u * DD + l16 * 8);
#pragma unroll
      for (int j = 0; j < 8; ++j) acc[j] += bf2f(a[j]);
    }
#pragma unroll
    for (int j = 0; j < 8; ++j) {
      acc[j] += __shfl_xor(acc[j], 16);
      acc[j] += __shfl_xor(acc[j], 32);
    }
    if (sub == 0) {
      u16x8 o;
#pragma unroll
      for (int j = 0; j < 8; ++j) o[j] = f2bf(acc[j]);
      *(u16x8*)(h0b + (size_t)v * DD + l16 * 8) = o;
    }
  }
}

// ---------------------------------------------------------------------------
// GEMM1: h1b = bf16(h0b @ W1^T + b1); BN1 stats into replica blockIdx&31.
// ---------------------------------------------------------------------------
__global__ __launch_bounds__(256) void k_gemm1(const unsigned short* __restrict__ A,
                                               const unsigned short* __restrict__ W,
                                               const float* __restrict__ bias,
                                               unsigned short* __restrict__ outb,
                                               float* __restrict__ sum1r,
                                               float* __restrict__ sumsq1r) {
  __shared__ float bsum[DD];
  __shared__ float bsq[DD];
  const int tid = threadIdx.x;
  const int wv = tid >> 6;
  const int lane = tid & 63;
  const int quad = lane >> 4;
  const int l16 = lane & 15;
  if (tid < DD) { bsum[tid] = 0.f; bsq[tid] = 0.f; }
  __syncthreads();

  const int rowbase = blockIdx.x * 64 + wv * 16 + l16;
  const int arow = rowbase < NN ? rowbase : NN - 1;
  const unsigned short* aptr = A + (size_t)arow * DD + quad * 8;

  f32x4 acc[8];
#pragma unroll
  for (int n = 0; n < 8; ++n) acc[n] = (f32x4){0.f, 0.f, 0.f, 0.f};
#pragma unroll
  for (int kk = 0; kk < 4; ++kk) {
    const bf16x8 af = *(const bf16x8*)(aptr + kk * 32);
#pragma unroll
    for (int n = 0; n < 8; ++n) {
      const bf16x8 bf =
          *(const bf16x8*)(W + (size_t)(n * 16 + l16) * DD + quad * 8 + kk * 32);
      acc[n] = __builtin_amdgcn_mfma_f32_16x16x32_bf16(af, bf, acc[n], 0, 0, 0);
    }
  }
  const int orow0 = blockIdx.x * 64 + wv * 16 + quad * 4;
#pragma unroll
  for (int n = 0; n < 8; ++n) {
    const int col = n * 16 + l16;
    const float bv = bias[col];
    float sv = 0.f, qv = 0.f;
#pragma unroll
    for (int r = 0; r < 4; ++r) {
      const int row = orow0 + r;
      if (row < NN) {
        const float o = acc[n][r] + bv;
        outb[(size_t)row * DD + col] = f2bf(o);
        sv += o; qv += o * o;
      }
    }
    sv += __shfl_xor(sv, 16); qv += __shfl_xor(qv, 16);
    sv += __shfl_xor(sv, 32); qv += __shfl_xor(qv, 32);
    if (quad == 0) { atomicAdd(&bsum[col], sv); atomicAdd(&bsq[col], qv); }
  }
  __syncthreads();
  if (tid < DD) {
    const int rep = (blockIdx.x & (NREP - 1)) * DD;
    atomicAdd(&sum1r[rep + tid], bsum[tid]);
    atomicAdd(&sumsq1r[rep + tid], bsq[tid]);
  }
}

// ---------------------------------------------------------------------------
// GEMM2: collapse sum1 replicas -> BN1 scale/shift in-block; A=relu(BN1(h1b))
// on the fly; out = h2b bf16; BN2 stats into replicas.
// ---------------------------------------------------------------------------
__global__ __launch_bounds__(256) void k_gemm2(const unsigned short* __restrict__ A,
                                               const float* __restrict__ sum1r,
                                               const float* __restrict__ sumsq1r,
                                               const float* __restrict__ gamma,
                                               const float* __restrict__ beta,
                                               const unsigned short* __restrict__ W,
                                               const float* __restrict__ bias,
                                               unsigned short* __restrict__ outb,
                                               float* __restrict__ sum2r,
                                               float* __restrict__ sumsq2r) {
  __shared__ float lsc[DD];
  __shared__ float lsh[DD];
  __shared__ float bsum[DD];
  __shared__ float bsq[DD];
  const int tid = threadIdx.x;
  const int wv = tid >> 6;
  const int lane = tid & 63;
  const int quad = lane >> 4;
  const int l16 = lane & 15;
  if (tid < DD) {
    float sm = 0.f, qm = 0.f;
#pragma unroll
    for (int r = 0; r < NREP; ++r) {
      sm += sum1r[r * DD + tid];
      qm += sumsq1r[r * DD + tid];
    }
    const float inv_n = 1.0f / (float)NN;
    const float mean = sm * inv_n;
    const float var = qm * inv_n - mean * mean;
    const float s = gamma[tid] * rsqrtf(var + BN_EPS);
    lsc[tid] = s;
    lsh[tid] = beta[tid] - mean * s;
    bsum[tid] = 0.f;
    bsq[tid] = 0.f;
  }
  __syncthreads();

  const int rowbase = blockIdx.x * 64 + wv * 16 + l16;
  const int arow = rowbase < NN ? rowbase : NN - 1;
  const unsigned short* aptr = A + (size_t)arow * DD + quad * 8;

  f32x4 acc[8];
#pragma unroll
  for (int n = 0; n < 8; ++n) acc[n] = (f32x4){0.f, 0.f, 0.f, 0.f};
#pragma unroll
  for (int kk = 0; kk < 4; ++kk) {
    const int kbase = kk * 32 + quad * 8;
    const u16x8 a = *(const u16x8*)(aptr + kk * 32);
    const float4 s0 = *(const float4*)&lsc[kbase];
    const float4 s1 = *(const float4*)&lsc[kbase + 4];
    const float4 h0 = *(const float4*)&lsh[kbase];
    const float4 h1 = *(const float4*)&lsh[kbase + 4];
    bf16x8 af;
    af[0] = (short)f2bf(fmaxf(fmaf(s0.x, bf2f(a[0]), h0.x), 0.f));
    af[1] = (short)f2bf(fmaxf(fmaf(s0.y, bf2f(a[1]), h0.y), 0.f));
    af[2] = (short)f2bf(fmaxf(fmaf(s0.z, bf2f(a[2]), h0.z), 0.f));
    af[3] = (short)f2bf(fmaxf(fmaf(s0.w, bf2f(a[3]), h0.w), 0.f));
    af[4] = (short)f2bf(fmaxf(fmaf(s1.x, bf2f(a[4]), h1.x), 0.f));
    af[5] = (short)f2bf(fmaxf(fmaf(s1.y, bf2f(a[5]), h1.y), 0.f));
    af[6] = (short)f2bf(fmaxf(fmaf(s1.z, bf2f(a[6]), h1.z), 0.f));
    af[7] = (short)f2bf(fmaxf(fmaf(s1.w, bf2f(a[7]), h1.w), 0.f));
#pragma unroll
    for (int n = 0; n < 8; ++n) {
      const bf16x8 bf =
          *(const bf16x8*)(W + (size_t)(n * 16 + l16) * DD + kbase);
      acc[n] = __builtin_amdgcn_mfma_f32_16x16x32_bf16(af, bf, acc[n], 0, 0, 0);
    }
  }
  const int orow0 = blockIdx.x * 64 + wv * 16 + quad * 4;
#pragma unroll
  for (int n = 0; n < 8; ++n) {
    const int col = n * 16 + l16;
    const float bv = bias[col];
    float sv = 0.f, qv = 0.f;
#pragma unroll
    for (int r = 0; r < 4; ++r) {
      const int row = orow0 + r;
      if (row < NN) {
        const float o = acc[n][r] + bv;
        outb[(size_t)row * DD + col] = f2bf(o);
        sv += o; qv += o * o;
      }
    }
    sv += __shfl_xor(sv, 16); qv += __shfl_xor(qv, 16);
    sv += __shfl_xor(sv, 32); qv += __shfl_xor(qv, 32);
    if (quad == 0) { atomicAdd(&bsum[col], sv); atomicAdd(&bsq[col], qv); }
  }
  __syncthreads();
  if (tid < DD) {
    const int rep = (blockIdx.x & (NREP - 1)) * DD;
    atomicAdd(&sum2r[rep + tid], bsum[tid]);
    atomicAdd(&sumsq2r[rep + tid], bsq[tid]);
  }
}

// K5: collapse BN2 replicas -> scale/shift in d_ws (replicas live in d_out,
// which k_bnrelu overwrites — must happen first).
__global__ void k_bnstats2(const float* __restrict__ sum2r,
                           const float* __restrict__ sumsq2r,
                           const float* __restrict__ gamma,
                           const float* __restrict__ beta,
                           float* __restrict__ scale,
                           float* __restrict__ shift) {
  const int c = threadIdx.x;
  float sm = 0.f, qm = 0.f;
#pragma unroll
  for (int r = 0; r < NREP; ++r) {
    sm += sum2r[r * DD + c];
    qm += sumsq2r[r * DD + c];
  }
  const float inv_n = 1.0f / (float)NN;
  const float mean = sm * inv_n;
  const float var = qm * inv_n - mean * mean;
  const float sc = gamma[c] * rsqrtf(var + BN_EPS);
  scale[c] = sc;
  shift[c] = beta[c] - mean * sc;
}

// K6: final BN2 + ReLU -> fp32 out
__global__ __launch_bounds__(256) void k_bnrelu(const unsigned short* __restrict__ in,
                                                const float* __restrict__ scale,
                                                const float* __restrict__ shift,
                                                float* __restrict__ out) {
  __shared__ float lsc[DD];
  __shared__ float lsh[DD];
  const int t = threadIdx.x;
  if (t < DD) {
    lsc[t] = scale[t];
    lsh[t] = shift[t];
  }
  __syncthreads();
  const int gid = blockIdx.x * 256 + t;
  const int c = (gid & 15) * 8;
  const u16x8 a = ((const u16x8*)in)[gid];
  const float4 sc0 = *(const float4*)&lsc[c];
  const float4 sc1 = *(const float4*)&lsc[c + 4];
  const float4 sh0 = *(const float4*)&lsh[c];
  const float4 sh1 = *(const float4*)&lsh[c + 4];
  float4 o0, o1;
  o0.x = fmaxf(fmaf(sc0.x, bf2f(a[0]), sh0.x), 0.f);
  o0.y = fmaxf(fmaf(sc0.y, bf2f(a[1]), sh0.y), 0.f);
  o0.z = fmaxf(fmaf(sc0.z, bf2f(a[2]), sh0.z), 0.f);
  o0.w = fmaxf(fmaf(sc0.w, bf2f(a[3]), sh0.w), 0.f);
  o1.x = fmaxf(fmaf(sc1.x, bf2f(a[4]), sh1.x), 0.f);
  o1.y = fmaxf(fmaf(sc1.y, bf2f(a[5]), sh1.y), 0.f);
  o1.z = fmaxf(fmaf(sc1.z, bf2f(a[6]), sh1.z), 0.f);
  o1.w = fmaxf(fmaf(sc1.w, bf2f(a[7]), sh1.w), 0.f);
  ((float4*)out)[gid * 2] = o0;
  ((float4*)out)[gid * 2 + 1] = o1;
}

// ---------------------------------------------------------------------------
extern "C" void kernel_launch(void* const* d_in, const int* in_sizes, int n_in,
                              void* d_out, int out_size, void* d_ws, size_t ws_size,
                              hipStream_t stream) {
  const float* x = (const float*)d_in[0];
  const int* ei = (const int*)d_in[1];
  const float* eps = (const float*)d_in[2];
  const float* W1 = (const float*)d_in[3];
  const float* b1 = (const float*)d_in[4];
  const float* g1 = (const float*)d_in[5];
  const float* be1 = (const float*)d_in[6];
  const float* W2 = (const float*)d_in[7];
  const float* b2 = (const float*)d_in[8];
  const float* g2 = (const float*)d_in[9];
  const float* be2 = (const float*)d_in[10];
  float* out = (float*)d_out;

  const int* rows = ei;
  const int* cols = ei + EE;

  // d_out scratch (dead before k_bnrelu writes d_out)
  int* bcur = (int*)d_out;                                  // NBUCK ints
  unsigned short* xb = (unsigned short*)d_out + 2000000;    // byte 4.0M
  unsigned int* bbuf = (unsigned int*)((char*)d_out + 16800000);  // 6.4MB
  unsigned short* W1b = (unsigned short*)d_out + 11640000;  // byte 23.28M
  unsigned short* W2b = (unsigned short*)d_out + 11680000;  // byte 23.36M
  float* reps = (float*)d_out + 5875000;                    // byte 23.5M, 64KB
  float* sum1r = reps;
  float* sumsq1r = reps + NREP * DD;
  float* sum2r = reps + 2 * NREP * DD;
  float* sumsq2r = reps + 3 * NREP * DD;

  unsigned short* h0b = (unsigned short*)d_ws;        // region A
  unsigned short* h1b = h0b + (size_t)NN * DD;        // region B
  unsigned short* h2b = h0b;                          // region A (reuse)
  float* stats = (float*)(h0b + (size_t)2 * NN * DD); // 4KB tail of d_ws
  float* scale2 = stats + 0;
  float* shift2 = stats + 128;

  // 1. prep: x/W1/W2 -> bf16, zero bcur + stat replicas
  k_prep<<<XCONV_B + 32, 256, 0, stream>>>(x, W1, W2, xb, W1b, W2b, bcur, reps);
  // 2. bin edges into fixed 64-row buckets (packed u32)
  k_bin0<<<BIN_BLOCKS, 256, 0, stream>>>(rows, cols, bcur, bbuf);
  // 3. per-bucket LDS sort + gather aggregation -> h0b
  k_aggb<<<NBUCK, 256, 0, stream>>>(xb, eps, bcur, bbuf, h0b);
  // 4-5. fused GEMM+BN layers (replicated stat atomics)
  k_gemm1<<<GEMM_B, 256, 0, stream>>>(h0b, W1b, b1, h1b, sum1r, sumsq1r);
  k_gemm2<<<GEMM_B, 256, 0, stream>>>(h1b, sum1r, sumsq1r, g1, be1, W2b, b2,
                                      h2b, sum2r, sumsq2r);
  // 6. collapse BN2 replicas into d_ws
  k_bnstats2<<<1, 128, 0, stream>>>(sum2r, sumsq2r, g2, be2, scale2, shift2);
  // 7. final BN2+ReLU -> fp32 out
  k_bnrelu<<<(NN * DD / 8) / 256, 256, 0, stream>>>(h2b, scale2, shift2, out);
}

// Round 10
// 207.836 us; speedup vs baseline: 4.4667x; 1.0302x over previous
//
#include <hip/hip_runtime.h>

#define NN 50000
#define EE 800000
#define DD 128
#define BN_EPS 1e-5f
#define XCONV_B 3125    // N*D/8/256
#define BIN_BLOCKS 200
#define BIN_EDGES 4000  // per block; 200*4000 == EE
#define NBUCK 782       // ceil(NN/64): 64-row buckets
#define BCAP 2048       // bucket capacity (mean 1023, Poisson tail ~e^-300)
#define NREP 32         // BN-stat replica count
#define LDA 136         // padded LDS A-tile stride (bf16): 272B -> 2-way banks

typedef __attribute__((ext_vector_type(8))) short bf16x8;
typedef __attribute__((ext_vector_type(4))) float f32x4;
typedef __attribute__((ext_vector_type(8))) unsigned short u16x8;

__device__ inline unsigned short f2bf(float f) {  // RNE fp32 -> bf16
  unsigned int u = __float_as_uint(f);
  u = (u + 0x7fffu + ((u >> 16) & 1u)) >> 16;
  return (unsigned short)u;
}
__device__ inline float bf2f(unsigned short b) {
  return __uint_as_float(((unsigned int)b) << 16);
}

// ---------------------------------------------------------------------------
// Memory plan (byte offsets into d_out, 25.6MB; scratch dead before k_bnrelu
// overwrites d_out with the fp32 result):
//   [0, +3128B)     bcur[NBUCK] bucket cursors
//   [4.0M, 16.8M)   xb  = bf16(x)                  (dies after k_aggemm1)
//   [16.8M, 23.2M)  bbuf = u32[NBUCK*BCAP] packed (row&63)<<16|col
//   [23.28M,+32KB)  W1b; [23.36M,+32KB) W2b
//   [23.5M, +64KB)  reps: sum1[NREP][128] | sumsq1 | sum2 | sumsq2
// d_ws (25.6MB + 4KB): region B h1b (aggemm1 out) | region A h2b (gemm2 out) |
//   stats at +25.6M: scale2[128] | shift2[128]
// 6 dispatches. Lessons pinned: grid.sync ~100us/sync on MI355X (R8);
// launch gap ~13us/dispatch (R7->R9 regression analysis).
// ---------------------------------------------------------------------------

// K0: fused prep — x->bf16, W1->bf16, W2->bf16, zero bcur + stat replicas
__global__ __launch_bounds__(256) void k_prep(const float* __restrict__ x,
                                              const float* __restrict__ W1,
                                              const float* __restrict__ W2,
                                              unsigned short* __restrict__ xb,
                                              unsigned short* __restrict__ W1b,
                                              unsigned short* __restrict__ W2b,
                                              int* __restrict__ bcur,
                                              float* __restrict__ reps) {
  const int b = blockIdx.x;
  const int t = threadIdx.x;
  if (b < XCONV_B) {
    const int gid = b * 256 + t;
    const float4 v0 = ((const float4*)x)[gid * 2];
    const float4 v1 = ((const float4*)x)[gid * 2 + 1];
    ushort4 o0, o1;
    o0.x = f2bf(v0.x); o0.y = f2bf(v0.y); o0.z = f2bf(v0.z); o0.w = f2bf(v0.w);
    o1.x = f2bf(v1.x); o1.y = f2bf(v1.y); o1.z = f2bf(v1.z); o1.w = f2bf(v1.w);
    ((ushort4*)xb)[gid * 2] = o0;
    ((ushort4*)xb)[gid * 2 + 1] = o1;
    if (gid < NBUCK) bcur[gid] = 0;
    if (gid < 4 * NREP * DD) reps[gid] = 0.0f;  // 16384 floats
  } else if (b < XCONV_B + 16) {
    const int gid = (b - XCONV_B) * 256 + t;
    const float4 v = ((const float4*)W1)[gid];
    ushort4 o;
    o.x = f2bf(v.x); o.y = f2bf(v.y); o.z = f2bf(v.z); o.w = f2bf(v.w);
    ((ushort4*)W1b)[gid] = o;
  } else {
    const int gid = (b - XCONV_B - 16) * 256 + t;
    const float4 v = ((const float4*)W2)[gid];
    ushort4 o;
    o.x = f2bf(v.x); o.y = f2bf(v.y); o.z = f2bf(v.z); o.w = f2bf(v.w);
    ((ushort4*)W2b)[gid] = o;
  }
}

// K1: bin edges into fixed-capacity 64-row buckets (block-private segments
// via one global reservation per bucket — keeps HBM write amp at 1x).
__global__ __launch_bounds__(256) void k_bin0(const int* __restrict__ rows,
                                              const int* __restrict__ cols,
                                              int* __restrict__ bcur,
                                              unsigned int* __restrict__ bbuf) {
  __shared__ int hist[NBUCK];
  __shared__ int lbase[NBUCK];
  const int t = threadIdx.x;
  for (int i = t; i < NBUCK; i += 256) hist[i] = 0;
  __syncthreads();
  const int e0 = blockIdx.x * BIN_EDGES;
  int er[16], ec[16];
#pragma unroll
  for (int i = 0; i < 16; ++i) {
    const int idx = t + i * 256;
    if (idx < BIN_EDGES) {
      er[i] = rows[e0 + idx];
      ec[i] = cols[e0 + idx];
      atomicAdd(&hist[er[i] >> 6], 1);
    }
  }
  __syncthreads();
  for (int i = t; i < NBUCK; i += 256) {
    const int c = hist[i];
    lbase[i] = (c > 0) ? atomicAdd(&bcur[i], c) : 0;
    hist[i] = 0;  // reuse as local placement cursor
  }
  __syncthreads();
#pragma unroll
  for (int i = 0; i < 16; ++i) {
    const int idx = t + i * 256;
    if (idx < BIN_EDGES) {
      const int bk = er[i] >> 6;
      const int lp = lbase[bk] + atomicAdd(&hist[bk], 1);
      if (lp < BCAP)  // statistically impossible overflow; memory-safety clamp
        bbuf[(size_t)bk * BCAP + lp] =
            ((unsigned)(er[i] & 63) << 16) | (unsigned)ec[i];
    }
  }
}

// K2: FUSED per-bucket aggregation + GEMM1. Block = bucket b = rows
// [64b,64b+64). Phase A: LDS counting sort + wave-per-row gather, aggregated
// bf16 rows land in a padded LDS tile (never round-trip to global). Phase B:
// MFMA GEMM reading A-fragments from LDS, B from global W1b; epilogue writes
// h1b + BN1 replica stats.
__global__ __launch_bounds__(256) void k_aggemm1(
    const unsigned short* __restrict__ xb, const float* __restrict__ eps,
    const int* __restrict__ bcnt, const unsigned int* __restrict__ bbuf,
    const unsigned short* __restrict__ W, const float* __restrict__ bias,
    unsigned short* __restrict__ outb, float* __restrict__ sum1r,
    float* __restrict__ sumsq1r) {
  __shared__ unsigned short scols[BCAP];      // 4KB sorted col ids
  __shared__ unsigned short sA[64 * LDA];     // 17.4KB padded A tile (bf16)
  __shared__ int rcnt[64];
  __shared__ int roff[65];
  __shared__ int sscan[256];
  __shared__ float bsum[DD];
  __shared__ float bsq[DD];
  const int t = threadIdx.x;
  const int bk = blockIdx.x;
  const int wv = t >> 6;
  const int lane = t & 63;
  const int sub = lane >> 4;   // == quad in phase B
  const int l16 = lane & 15;

  int n = bcnt[bk];
  n = n < BCAP ? n : BCAP;
  if (t < 64) rcnt[t] = 0;
  if (t < DD) { bsum[t] = 0.f; bsq[t] = 0.f; }
  __syncthreads();

  // ---- phase A1: load bucket entries + per-row count
  unsigned int ent[8];
  int nl = 0;
  for (int i = t; i < n; i += 256) {
    const unsigned int e = bbuf[(size_t)bk * BCAP + i];
    ent[nl++] = e;
    atomicAdd(&rcnt[e >> 16], 1);
  }
  __syncthreads();
  // exclusive scan of 64 row-counts
  sscan[t] = (t < 64) ? rcnt[t] : 0;
  __syncthreads();
#pragma unroll
  for (int off = 1; off < 64; off <<= 1) {
    const int v = (t >= off) ? sscan[t - off] : 0;
    __syncthreads();
    sscan[t] += v;
    __syncthreads();
  }
  if (t < 64) {
    roff[t] = sscan[t] - rcnt[t];
    rcnt[t] = 0;  // reuse as placement cursor
  }
  if (t == 63) roff[64] = sscan[63];
  __syncthreads();
  // place col ids row-sorted
  for (int i = 0; i < nl; ++i) {
    const int r = ent[i] >> 16;
    const int pos = roff[r] + atomicAdd(&rcnt[r], 1);
    scols[pos] = (unsigned short)(ent[i] & 0xffffu);
  }
  __syncthreads();

  // ---- phase A2: gather-aggregate; wave wv owns rows wv, wv+4, ...
  {
    const float s = 1.0f + eps[0];
    for (int r = wv; r < 64; r += 4) {
      const int v = bk * 64 + r;
      float acc[8];
#pragma unroll
      for (int j = 0; j < 8; ++j) acc[j] = 0.f;
      if (v < NN) {
        if (sub == 0) {
          const u16x8 a = *(const u16x8*)(xb + (size_t)v * DD + l16 * 8);
#pragma unroll
          for (int j = 0; j < 8; ++j) acc[j] = s * bf2f(a[j]);
        }
        const int beg = roff[r];
        const int end = roff[r + 1];
        int i = beg + sub;
        for (; i + 4 < end; i += 8) {
          const int u0 = scols[i];
          const int u1 = scols[i + 4];
          const u16x8 a = *(const u16x8*)(xb + (size_t)u0 * DD + l16 * 8);
          const u16x8 b = *(const u16x8*)(xb + (size_t)u1 * DD + l16 * 8);
#pragma unroll
          for (int j = 0; j < 8; ++j) acc[j] += bf2f(a[j]) + bf2f(b[j]);
        }
        if (i < end) {
          const int u = scols[i];
          const u16x8 a = *(const u16x8*)(xb + (size_t)u * DD + l16 * 8);
#pragma unroll
          for (int j = 0; j < 8; ++j) acc[j] += bf2f(a[j]);
        }
      }
#pragma unroll
      for (int j = 0; j < 8; ++j) {
        acc[j] += __shfl_xor(acc[j], 16);
        acc[j] += __shfl_xor(acc[j], 32);
      }
      if (sub == 0) {
        u16x8 o;
#pragma unroll
        for (int j = 0; j < 8; ++j) o[j] = f2bf(acc[j]);
        *(u16x8*)(&sA[r * LDA + l16 * 8]) = o;  // 2-way bank alias: free
      }
    }
  }
  __syncthreads();

  // ---- phase B: MFMA GEMM, A from LDS tile, B from global W (bf16)
  f32x4 acc[8];
#pragma unroll
  for (int nn = 0; nn < 8; ++nn) acc[nn] = (f32x4){0.f, 0.f, 0.f, 0.f};
#pragma unroll
  for (int kk = 0; kk < 4; ++kk) {
    const bf16x8 af =
        *(const bf16x8*)(&sA[(wv * 16 + l16) * LDA + kk * 32 + sub * 8]);
#pragma unroll
    for (int nn = 0; nn < 8; ++nn) {
      const bf16x8 bf =
          *(const bf16x8*)(W + (size_t)(nn * 16 + l16) * DD + sub * 8 + kk * 32);
      acc[nn] = __builtin_amdgcn_mfma_f32_16x16x32_bf16(af, bf, acc[nn], 0, 0, 0);
    }
  }
  const int orow0 = bk * 64 + wv * 16 + sub * 4;
#pragma unroll
  for (int nn = 0; nn < 8; ++nn) {
    const int col = nn * 16 + l16;
    const float bv = bias[col];
    float sv = 0.f, qv = 0.f;
#pragma unroll
    for (int r = 0; r < 4; ++r) {
      const int row = orow0 + r;
      if (row < NN) {
        const float o = acc[nn][r] + bv;
        outb[(size_t)row * DD + col] = f2bf(o);
        sv += o; qv += o * o;
      }
    }
    sv += __shfl_xor(sv, 16); qv += __shfl_xor(qv, 16);
    sv += __shfl_xor(sv, 32); qv += __shfl_xor(qv, 32);
    if (sub == 0) { atomicAdd(&bsum[col], sv); atomicAdd(&bsq[col], qv); }
  }
  __syncthreads();
  if (t < DD) {
    const int rep = (bk & (NREP - 1)) * DD;
    atomicAdd(&sum1r[rep + t], bsum[t]);
    atomicAdd(&sumsq1r[rep + t], bsq[t]);
  }
}

// ---------------------------------------------------------------------------
// GEMM2: collapse sum1 replicas -> BN1 scale/shift in-block; A=relu(BN1(h1b))
// on the fly; out = h2b bf16; BN2 stats into replicas.
// ---------------------------------------------------------------------------
__global__ __launch_bounds__(256) void k_gemm2(const unsigned short* __restrict__ A,
                                               const float* __restrict__ sum1r,
                                               const float* __restrict__ sumsq1r,
                                               const float* __restrict__ gamma,
                                               const float* __restrict__ beta,
                                               const unsigned short* __restrict__ W,
                                               const float* __restrict__ bias,
                                               unsigned short* __restrict__ outb,
                                               float* __restrict__ sum2r,
                                               float* __restrict__ sumsq2r) {
  __shared__ float lsc[DD];
  __shared__ float lsh[DD];
  __shared__ float bsum[DD];
  __shared__ float bsq[DD];
  const int tid = threadIdx.x;
  const int wv = tid >> 6;
  const int lane = tid & 63;
  const int quad = lane >> 4;
  const int l16 = lane & 15;
  if (tid < DD) {
    float sm = 0.f, qm = 0.f;
#pragma unroll
    for (int r = 0; r < NREP; ++r) {
      sm += sum1r[r * DD + tid];
      qm += sumsq1r[r * DD + tid];
    }
    const float inv_n = 1.0f / (float)NN;
    const float mean = sm * inv_n;
    const float var = qm * inv_n - mean * mean;
    const float s = gamma[tid] * rsqrtf(var + BN_EPS);
    lsc[tid] = s;
    lsh[tid] = beta[tid] - mean * s;
    bsum[tid] = 0.f;
    bsq[tid] = 0.f;
  }
  __syncthreads();

  const int rowbase = blockIdx.x * 64 + wv * 16 + l16;
  const int arow = rowbase < NN ? rowbase : NN - 1;
  const unsigned short* aptr = A + (size_t)arow * DD + quad * 8;

  f32x4 acc[8];
#pragma unroll
  for (int n = 0; n < 8; ++n) acc[n] = (f32x4){0.f, 0.f, 0.f, 0.f};
#pragma unroll
  for (int kk = 0; kk < 4; ++kk) {
    const int kbase = kk * 32 + quad * 8;
    const u16x8 a = *(const u16x8*)(aptr + kk * 32);
    const float4 s0 = *(const float4*)&lsc[kbase];
    const float4 s1 = *(const float4*)&lsc[kbase + 4];
    const float4 h0 = *(const float4*)&lsh[kbase];
    const float4 h1 = *(const float4*)&lsh[kbase + 4];
    bf16x8 af;
    af[0] = (short)f2bf(fmaxf(fmaf(s0.x, bf2f(a[0]), h0.x), 0.f));
    af[1] = (short)f2bf(fmaxf(fmaf(s0.y, bf2f(a[1]), h0.y), 0.f));
    af[2] = (short)f2bf(fmaxf(fmaf(s0.z, bf2f(a[2]), h0.z), 0.f));
    af[3] = (short)f2bf(fmaxf(fmaf(s0.w, bf2f(a[3]), h0.w), 0.f));
    af[4] = (short)f2bf(fmaxf(fmaf(s1.x, bf2f(a[4]), h1.x), 0.f));
    af[5] = (short)f2bf(fmaxf(fmaf(s1.y, bf2f(a[5]), h1.y), 0.f));
    af[6] = (short)f2bf(fmaxf(fmaf(s1.z, bf2f(a[6]), h1.z), 0.f));
    af[7] = (short)f2bf(fmaxf(fmaf(s1.w, bf2f(a[7]), h1.w), 0.f));
#pragma unroll
    for (int n = 0; n < 8; ++n) {
      const bf16x8 bf =
          *(const bf16x8*)(W + (size_t)(n * 16 + l16) * DD + kbase);
      acc[n] = __builtin_amdgcn_mfma_f32_16x16x32_bf16(af, bf, acc[n], 0, 0, 0);
    }
  }
  const int orow0 = blockIdx.x * 64 + wv * 16 + quad * 4;
#pragma unroll
  for (int n = 0; n < 8; ++n) {
    const int col = n * 16 + l16;
    const float bv = bias[col];
    float sv = 0.f, qv = 0.f;
#pragma unroll
    for (int r = 0; r < 4; ++r) {
      const int row = orow0 + r;
      if (row < NN) {
        const float o = acc[n][r] + bv;
        outb[(size_t)row * DD + col] = f2bf(o);
        sv += o; qv += o * o;
      }
    }
    sv += __shfl_xor(sv, 16); qv += __shfl_xor(qv, 16);
    sv += __shfl_xor(sv, 32); qv += __shfl_xor(qv, 32);
    if (quad == 0) { atomicAdd(&bsum[col], sv); atomicAdd(&bsq[col], qv); }
  }
  __syncthreads();
  if (tid < DD) {
    const int rep = (blockIdx.x & (NREP - 1)) * DD;
    atomicAdd(&sum2r[rep + tid], bsum[tid]);
    atomicAdd(&sumsq2r[rep + tid], bsq[tid]);
  }
}

// K4: collapse BN2 replicas -> scale/shift in d_ws (replicas live in d_out,
// which k_bnrelu overwrites — must happen first).
__global__ void k_bnstats2(const float* __restrict__ sum2r,
                           const float* __restrict__ sumsq2r,
                           const float* __restrict__ gamma,
                           const float* __restrict__ beta,
                           float* __restrict__ scale,
                           float* __restrict__ shift) {
  const int c = threadIdx.x;
  float sm = 0.f, qm = 0.f;
#pragma unroll
  for (int r = 0; r < NREP; ++r) {
    sm += sum2r[r * DD + c];
    qm += sumsq2r[r * DD + c];
  }
  const float inv_n = 1.0f / (float)NN;
  const float mean = sm * inv_n;
  const float var = qm * inv_n - mean * mean;
  const float sc = gamma[c] * rsqrtf(var + BN_EPS);
  scale[c] = sc;
  shift[c] = beta[c] - mean * sc;
}

// K5: final BN2 + ReLU -> fp32 out
__global__ __launch_bounds__(256) void k_bnrelu(const unsigned short* __restrict__ in,
                                                const float* __restrict__ scale,
                                                const float* __restrict__ shift,
                                                float* __restrict__ out) {
  __shared__ float lsc[DD];
  __shared__ float lsh[DD];
  const int t = threadIdx.x;
  if (t < DD) {
    lsc[t] = scale[t];
    lsh[t] = shift[t];
  }
  __syncthreads();
  const int gid = blockIdx.x * 256 + t;
  const int c = (gid & 15) * 8;
  const u16x8 a = ((const u16x8*)in)[gid];
  const float4 sc0 = *(const float4*)&lsc[c];
  const float4 sc1 = *(const float4*)&lsc[c + 4];
  const float4 sh0 = *(const float4*)&lsh[c];
  const float4 sh1 = *(const float4*)&lsh[c + 4];
  float4 o0, o1;
  o0.x = fmaxf(fmaf(sc0.x, bf2f(a[0]), sh0.x), 0.f);
  o0.y = fmaxf(fmaf(sc0.y, bf2f(a[1]), sh0.y), 0.f);
  o0.z = fmaxf(fmaf(sc0.z, bf2f(a[2]), sh0.z), 0.f);
  o0.w = fmaxf(fmaf(sc0.w, bf2f(a[3]), sh0.w), 0.f);
  o1.x = fmaxf(fmaf(sc1.x, bf2f(a[4]), sh1.x), 0.f);
  o1.y = fmaxf(fmaf(sc1.y, bf2f(a[5]), sh1.y), 0.f);
  o1.z = fmaxf(fmaf(sc1.z, bf2f(a[6]), sh1.z), 0.f);
  o1.w = fmaxf(fmaf(sc1.w, bf2f(a[7]), sh1.w), 0.f);
  ((float4*)out)[gid * 2] = o0;
  ((float4*)out)[gid * 2 + 1] = o1;
}

// ---------------------------------------------------------------------------
extern "C" void kernel_launch(void* const* d_in, const int* in_sizes, int n_in,
                              void* d_out, int out_size, void* d_ws, size_t ws_size,
                              hipStream_t stream) {
  const float* x = (const float*)d_in[0];
  const int* ei = (const int*)d_in[1];
  const float* eps = (const float*)d_in[2];
  const float* W1 = (const float*)d_in[3];
  const float* b1 = (const float*)d_in[4];
  const float* g1 = (const float*)d_in[5];
  const float* be1 = (const float*)d_in[6];
  const float* W2 = (const float*)d_in[7];
  const float* b2 = (const float*)d_in[8];
  const float* g2 = (const float*)d_in[9];
  const float* be2 = (const float*)d_in[10];
  float* out = (float*)d_out;

  const int* rows = ei;
  const int* cols = ei + EE;

  // d_out scratch (dead before k_bnrelu writes d_out)
  int* bcur = (int*)d_out;                                  // NBUCK ints
  unsigned short* xb = (unsigned short*)d_out + 2000000;    // byte 4.0M
  unsigned int* bbuf = (unsigned int*)((char*)d_out + 16800000);  // 6.4MB
  unsigned short* W1b = (unsigned short*)d_out + 11640000;  // byte 23.28M
  unsigned short* W2b = (unsigned short*)d_out + 11680000;  // byte 23.36M
  float* reps = (float*)d_out + 5875000;                    // byte 23.5M, 64KB
  float* sum1r = reps;
  float* sumsq1r = reps + NREP * DD;
  float* sum2r = reps + 2 * NREP * DD;
  float* sumsq2r = reps + 3 * NREP * DD;

  unsigned short* h1b = (unsigned short*)d_ws;        // region B (aggemm1 out)
  unsigned short* h2b = h1b + (size_t)NN * DD;        // region A (gemm2 out)
  float* stats = (float*)(h1b + (size_t)2 * NN * DD); // 4KB tail of d_ws
  float* scale2 = stats + 0;
  float* shift2 = stats + 128;

  // 1. prep: x/W1/W2 -> bf16, zero bcur + stat replicas
  k_prep<<<XCONV_B + 32, 256, 0, stream>>>(x, W1, W2, xb, W1b, W2b, bcur, reps);
  // 2. bin edges into fixed 64-row buckets (packed u32)
  k_bin0<<<BIN_BLOCKS, 256, 0, stream>>>(rows, cols, bcur, bbuf);
  // 3. FUSED per-bucket sort + gather aggregation + GEMM1 -> h1b, BN1 stats
  k_aggemm1<<<NBUCK, 256, 0, stream>>>(xb, eps, bcur, bbuf, W1b, b1, h1b,
                                       sum1r, sumsq1r);
  // 4. GEMM2 (BN1+ReLU on the fly) -> h2b, BN2 stats
  k_gemm2<<<NBUCK, 256, 0, stream>>>(h1b, sum1r, sumsq1r, g1, be1, W2b, b2,
                                     h2b, sum2r, sumsq2r);
  // 5. collapse BN2 replicas into d_ws
  k_bnstats2<<<1, 128, 0, stream>>>(sum2r, sumsq2r, g2, be2, scale2, shift2);
  // 6. final BN2+ReLU -> fp32 out
  k_bnrelu<<<(NN * DD / 8) / 256, 256, 0, stream>>>(h2b, scale2, shift2, out);
}

// Round 11
// 204.673 us; speedup vs baseline: 4.5357x; 1.0155x over previous
//
#include <hip/hip_runtime.h>

#define NN 50000
#define EE 800000
#define DD 128
#define BN_EPS 1e-5f
#define XCONV_B 3125    // N*D/8/256
#define BIN_BLOCKS 200
#define BIN_EDGES 4000  // per block; 200*4000 == EE
#define NBUCK 1563      // ceil(50000/32): 32-row buckets
#define BCAP 1024       // bucket capacity (mean 512, ~22 sigma headroom)
#define NREP 32         // BN-stat replica count
#define GEMM_B 782      // ceil(NN/64) for gemm2
#define LDA 136         // padded LDS A-tile stride (bf16): 272B -> 2-way banks

typedef __attribute__((ext_vector_type(8))) short bf16x8;
typedef __attribute__((ext_vector_type(4))) float f32x4;
typedef __attribute__((ext_vector_type(8))) unsigned short u16x8;

__device__ inline unsigned short f2bf(float f) {  // RNE fp32 -> bf16
  unsigned int u = __float_as_uint(f);
  u = (u + 0x7fffu + ((u >> 16) & 1u)) >> 16;
  return (unsigned short)u;
}
__device__ inline float bf2f(unsigned short b) {
  return __uint_as_float(((unsigned int)b) << 16);
}

// ---------------------------------------------------------------------------
// Memory plan (byte offsets into d_out, 25.6MB; scratch dead before k_bnrelu
// overwrites d_out with the fp32 result):
//   [0, +6252B)     bcur[NBUCK] bucket cursors
//   [4.0M, 16.8M)   xb  = bf16(x)                  (dies after k_aggemm1)
//   [16.8M, 23.2M)  bbuf = u32[NBUCK*BCAP] packed (row&31)<<16|col
//   [23.28M,+32KB)  W1b; [23.36M,+32KB) W2b
//   [23.5M, +64KB)  reps: sum1[NREP][128] | sumsq1 | sum2 | sumsq2
// d_ws (25.6MB + 4KB): h1b | h2b | stats tail: scale2[128] | shift2[128]
// 6 dispatches. Lessons pinned: grid.sync ~100us/sync (R8); launch gap
// ~13us/dispatch (R7-R9); 64-row/782-block aggemm was grid-limited at
// 28% occupancy (R10) -> 32-row/1563-block + 4-deep gather MLP here.
// ---------------------------------------------------------------------------

// K0: fused prep — x->bf16, W1->bf16, W2->bf16, zero bcur + stat replicas
__global__ __launch_bounds__(256) void k_prep(const float* __restrict__ x,
                                              const float* __restrict__ W1,
                                              const float* __restrict__ W2,
                                              unsigned short* __restrict__ xb,
                                              unsigned short* __restrict__ W1b,
                                              unsigned short* __restrict__ W2b,
                                              int* __restrict__ bcur,
                                              float* __restrict__ reps) {
  const int b = blockIdx.x;
  const int t = threadIdx.x;
  if (b < XCONV_B) {
    const int gid = b * 256 + t;
    const float4 v0 = ((const float4*)x)[gid * 2];
    const float4 v1 = ((const float4*)x)[gid * 2 + 1];
    ushort4 o0, o1;
    o0.x = f2bf(v0.x); o0.y = f2bf(v0.y); o0.z = f2bf(v0.z); o0.w = f2bf(v0.w);
    o1.x = f2bf(v1.x); o1.y = f2bf(v1.y); o1.z = f2bf(v1.z); o1.w = f2bf(v1.w);
    ((ushort4*)xb)[gid * 2] = o0;
    ((ushort4*)xb)[gid * 2 + 1] = o1;
    if (gid < NBUCK) bcur[gid] = 0;
    if (gid < 4 * NREP * DD) reps[gid] = 0.0f;  // 16384 floats
  } else if (b < XCONV_B + 16) {
    const int gid = (b - XCONV_B) * 256 + t;
    const float4 v = ((const float4*)W1)[gid];
    ushort4 o;
    o.x = f2bf(v.x); o.y = f2bf(v.y); o.z = f2bf(v.z); o.w = f2bf(v.w);
    ((ushort4*)W1b)[gid] = o;
  } else {
    const int gid = (b - XCONV_B - 16) * 256 + t;
    const float4 v = ((const float4*)W2)[gid];
    ushort4 o;
    o.x = f2bf(v.x); o.y = f2bf(v.y); o.z = f2bf(v.z); o.w = f2bf(v.w);
    ((ushort4*)W2b)[gid] = o;
  }
}

// K1: bin edges into fixed-capacity 32-row buckets (block-private segments
// via one global reservation per bucket — HBM write amp stays 1x).
__global__ __launch_bounds__(256) void k_bin0(const int* __restrict__ rows,
                                              const int* __restrict__ cols,
                                              int* __restrict__ bcur,
                                              unsigned int* __restrict__ bbuf) {
  __shared__ int hist[NBUCK];
  __shared__ int lbase[NBUCK];
  const int t = threadIdx.x;
  for (int i = t; i < NBUCK; i += 256) hist[i] = 0;
  __syncthreads();
  const int e0 = blockIdx.x * BIN_EDGES;
  int er[16], ec[16];
#pragma unroll
  for (int i = 0; i < 16; ++i) {
    const int idx = t + i * 256;
    if (idx < BIN_EDGES) {
      er[i] = rows[e0 + idx];
      ec[i] = cols[e0 + idx];
      atomicAdd(&hist[er[i] >> 5], 1);
    }
  }
  __syncthreads();
  for (int i = t; i < NBUCK; i += 256) {
    const int c = hist[i];
    lbase[i] = (c > 0) ? atomicAdd(&bcur[i], c) : 0;
    hist[i] = 0;  // reuse as local placement cursor
  }
  __syncthreads();
#pragma unroll
  for (int i = 0; i < 16; ++i) {
    const int idx = t + i * 256;
    if (idx < BIN_EDGES) {
      const int bk = er[i] >> 5;
      const int lp = lbase[bk] + atomicAdd(&hist[bk], 1);
      if (lp < BCAP)  // statistically impossible overflow; memory-safety clamp
        bbuf[(size_t)bk * BCAP + lp] =
            ((unsigned)(er[i] & 31) << 16) | (unsigned)ec[i];
    }
  }
}

// K2: FUSED per-bucket aggregation + GEMM1. Block = bucket b = rows
// [32b,32b+32), 128 threads (2 waves). Phase A: LDS counting sort +
// wave-per-row gather with 4-deep load pipelining; aggregated bf16 rows land
// in a padded LDS tile. Phase B: MFMA GEMM (A from LDS, B=W1b from global);
// epilogue writes h1b + BN1 replica stats.
__global__ __launch_bounds__(128) void k_aggemm1(
    const unsigned short* __restrict__ xb, const float* __restrict__ eps,
    const int* __restrict__ bcnt, const unsigned int* __restrict__ bbuf,
    const unsigned short* __restrict__ W, const float* __restrict__ bias,
    unsigned short* __restrict__ outb, float* __restrict__ sum1r,
    float* __restrict__ sumsq1r) {
  __shared__ unsigned short scols[BCAP];   // 2KB sorted col ids
  __shared__ unsigned short sA[32 * LDA];  // 8.7KB padded A tile (bf16)
  __shared__ int rcnt[32];
  __shared__ int roff[33];
  __shared__ int sscan[128];
  __shared__ float bsum[DD];
  __shared__ float bsq[DD];
  const int t = threadIdx.x;
  const int bk = blockIdx.x;
  const int wv = t >> 6;       // 0..1
  const int lane = t & 63;
  const int sub = lane >> 4;   // 0..3 (== quad in phase B)
  const int l16 = lane & 15;

  int n = bcnt[bk];
  n = n < BCAP ? n : BCAP;
  if (t < 32) rcnt[t] = 0;
  bsum[t] = 0.f;
  bsq[t] = 0.f;
  __syncthreads();

  // ---- phase A1: load bucket entries + per-row count
  unsigned int ent[8];
  int nl = 0;
  for (int i = t; i < n; i += 128) {
    const unsigned int e = bbuf[(size_t)bk * BCAP + i];
    ent[nl++] = e;
    atomicAdd(&rcnt[e >> 16], 1);
  }
  __syncthreads();
  // exclusive scan of 32 row-counts
  sscan[t] = (t < 32) ? rcnt[t] : 0;
  __syncthreads();
#pragma unroll
  for (int off = 1; off < 32; off <<= 1) {
    const int v = (t >= off) ? sscan[t - off] : 0;
    __syncthreads();
    sscan[t] += v;
    __syncthreads();
  }
  if (t < 32) {
    roff[t] = sscan[t] - rcnt[t];
    rcnt[t] = 0;  // reuse as placement cursor
  }
  if (t == 31) roff[32] = sscan[31];
  __syncthreads();
  // place col ids row-sorted
  for (int i = 0; i < nl; ++i) {
    const int r = ent[i] >> 16;
    const int pos = roff[r] + atomicAdd(&rcnt[r], 1);
    scols[pos] = (unsigned short)(ent[i] & 0xffffu);
  }
  __syncthreads();

  // ---- phase A2: gather-aggregate; wave wv owns rows wv, wv+2, ...
  {
    const float s = 1.0f + eps[0];
    for (int r = wv; r < 32; r += 2) {
      const int v = bk * 32 + r;
      float acc[8];
#pragma unroll
      for (int j = 0; j < 8; ++j) acc[j] = 0.f;
      if (v < NN) {
        if (sub == 0) {
          const u16x8 a = *(const u16x8*)(xb + (size_t)v * DD + l16 * 8);
#pragma unroll
          for (int j = 0; j < 8; ++j) acc[j] = s * bf2f(a[j]);
        }
        const int beg = roff[r];
        const int end = roff[r + 1];
        int i = beg + sub;
        // 4-deep load pipeline per sub (16 rows in flight per wave)
        for (; i + 12 < end; i += 16) {
          const int u0 = scols[i];
          const int u1 = scols[i + 4];
          const int u2 = scols[i + 8];
          const int u3 = scols[i + 12];
          const u16x8 a = *(const u16x8*)(xb + (size_t)u0 * DD + l16 * 8);
          const u16x8 b = *(const u16x8*)(xb + (size_t)u1 * DD + l16 * 8);
          const u16x8 c = *(const u16x8*)(xb + (size_t)u2 * DD + l16 * 8);
          const u16x8 d = *(const u16x8*)(xb + (size_t)u3 * DD + l16 * 8);
#pragma unroll
          for (int j = 0; j < 8; ++j)
            acc[j] += (bf2f(a[j]) + bf2f(b[j])) + (bf2f(c[j]) + bf2f(d[j]));
        }
        for (; i + 4 < end; i += 8) {
          const int u0 = scols[i];
          const int u1 = scols[i + 4];
          const u16x8 a = *(const u16x8*)(xb + (size_t)u0 * DD + l16 * 8);
          const u16x8 b = *(const u16x8*)(xb + (size_t)u1 * DD + l16 * 8);
#pragma unroll
          for (int j = 0; j < 8; ++j) acc[j] += bf2f(a[j]) + bf2f(b[j]);
        }
        if (i < end) {
          const int u = scols[i];
          const u16x8 a = *(const u16x8*)(xb + (size_t)u * DD + l16 * 8);
#pragma unroll
          for (int j = 0; j < 8; ++j) acc[j] += bf2f(a[j]);
        }
      }
#pragma unroll
      for (int j = 0; j < 8; ++j) {
        acc[j] += __shfl_xor(acc[j], 16);
        acc[j] += __shfl_xor(acc[j], 32);
      }
      if (sub == 0) {
        u16x8 o;
#pragma unroll
        for (int j = 0; j < 8; ++j) o[j] = f2bf(acc[j]);
        *(u16x8*)(&sA[r * LDA + l16 * 8]) = o;  // 2-way bank alias: free
      }
    }
  }
  __syncthreads();

  // ---- phase B: MFMA GEMM, A from LDS tile, B from global W (bf16)
  f32x4 acc[8];
#pragma unroll
  for (int nn = 0; nn < 8; ++nn) acc[nn] = (f32x4){0.f, 0.f, 0.f, 0.f};
#pragma unroll
  for (int kk = 0; kk < 4; ++kk) {
    const bf16x8 af =
        *(const bf16x8*)(&sA[(wv * 16 + l16) * LDA + kk * 32 + sub * 8]);
#pragma unroll
    for (int nn = 0; nn < 8; ++nn) {
      const bf16x8 bf =
          *(const bf16x8*)(W + (size_t)(nn * 16 + l16) * DD + sub * 8 + kk * 32);
      acc[nn] = __builtin_amdgcn_mfma_f32_16x16x32_bf16(af, bf, acc[nn], 0, 0, 0);
    }
  }
  const int orow0 = bk * 32 + wv * 16 + sub * 4;
#pragma unroll
  for (int nn = 0; nn < 8; ++nn) {
    const int col = nn * 16 + l16;
    const float bv = bias[col];
    float sv = 0.f, qv = 0.f;
#pragma unroll
    for (int r = 0; r < 4; ++r) {
      const int row = orow0 + r;
      if (row < NN) {
        const float o = acc[nn][r] + bv;
        outb[(size_t)row * DD + col] = f2bf(o);
        sv += o; qv += o * o;
      }
    }
    sv += __shfl_xor(sv, 16); qv += __shfl_xor(qv, 16);
    sv += __shfl_xor(sv, 32); qv += __shfl_xor(qv, 32);
    if (sub == 0) { atomicAdd(&bsum[col], sv); atomicAdd(&bsq[col], qv); }
  }
  __syncthreads();
  {
    const int rep = (bk & (NREP - 1)) * DD;
    atomicAdd(&sum1r[rep + t], bsum[t]);
    atomicAdd(&sumsq1r[rep + t], bsq[t]);
  }
}

// ---------------------------------------------------------------------------
// GEMM2: collapse sum1 replicas -> BN1 scale/shift in-block; A=relu(BN1(h1b))
// on the fly; out = h2b bf16; BN2 stats into replicas.
// ---------------------------------------------------------------------------
__global__ __launch_bounds__(256) void k_gemm2(const unsigned short* __restrict__ A,
                                               const float* __restrict__ sum1r,
                                               const float* __restrict__ sumsq1r,
                                               const float* __restrict__ gamma,
                                               const float* __restrict__ beta,
                                               const unsigned short* __restrict__ W,
                                               const float* __restrict__ bias,
                                               unsigned short* __restrict__ outb,
                                               float* __restrict__ sum2r,
                                               float* __restrict__ sumsq2r) {
  __shared__ float lsc[DD];
  __shared__ float lsh[DD];
  __shared__ float bsum[DD];
  __shared__ float bsq[DD];
  const int tid = threadIdx.x;
  const int wv = tid >> 6;
  const int lane = tid & 63;
  const int quad = lane >> 4;
  const int l16 = lane & 15;
  if (tid < DD) {
    float sm = 0.f, qm = 0.f;
#pragma unroll
    for (int r = 0; r < NREP; ++r) {
      sm += sum1r[r * DD + tid];
      qm += sumsq1r[r * DD + tid];
    }
    const float inv_n = 1.0f / (float)NN;
    const float mean = sm * inv_n;
    const float var = qm * inv_n - mean * mean;
    const float s = gamma[tid] * rsqrtf(var + BN_EPS);
    lsc[tid] = s;
    lsh[tid] = beta[tid] - mean * s;
    bsum[tid] = 0.f;
    bsq[tid] = 0.f;
  }
  __syncthreads();

  const int rowbase = blockIdx.x * 64 + wv * 16 + l16;
  const int arow = rowbase < NN ? rowbase : NN - 1;
  const unsigned short* aptr = A + (size_t)arow * DD + quad * 8;

  f32x4 acc[8];
#pragma unroll
  for (int n = 0; n < 8; ++n) acc[n] = (f32x4){0.f, 0.f, 0.f, 0.f};
#pragma unroll
  for (int kk = 0; kk < 4; ++kk) {
    const int kbase = kk * 32 + quad * 8;
    const u16x8 a = *(const u16x8*)(aptr + kk * 32);
    const float4 s0 = *(const float4*)&lsc[kbase];
    const float4 s1 = *(const float4*)&lsc[kbase + 4];
    const float4 h0 = *(const float4*)&lsh[kbase];
    const float4 h1 = *(const float4*)&lsh[kbase + 4];
    bf16x8 af;
    af[0] = (short)f2bf(fmaxf(fmaf(s0.x, bf2f(a[0]), h0.x), 0.f));
    af[1] = (short)f2bf(fmaxf(fmaf(s0.y, bf2f(a[1]), h0.y), 0.f));
    af[2] = (short)f2bf(fmaxf(fmaf(s0.z, bf2f(a[2]), h0.z), 0.f));
    af[3] = (short)f2bf(fmaxf(fmaf(s0.w, bf2f(a[3]), h0.w), 0.f));
    af[4] = (short)f2bf(fmaxf(fmaf(s1.x, bf2f(a[4]), h1.x), 0.f));
    af[5] = (short)f2bf(fmaxf(fmaf(s1.y, bf2f(a[5]), h1.y), 0.f));
    af[6] = (short)f2bf(fmaxf(fmaf(s1.z, bf2f(a[6]), h1.z), 0.f));
    af[7] = (short)f2bf(fmaxf(fmaf(s1.w, bf2f(a[7]), h1.w), 0.f));
#pragma unroll
    for (int n = 0; n < 8; ++n) {
      const bf16x8 bf =
          *(const bf16x8*)(W + (size_t)(n * 16 + l16) * DD + kbase);
      acc[n] = __builtin_amdgcn_mfma_f32_16x16x32_bf16(af, bf, acc[n], 0, 0, 0);
    }
  }
  const int orow0 = blockIdx.x * 64 + wv * 16 + quad * 4;
#pragma unroll
  for (int n = 0; n < 8; ++n) {
    const int col = n * 16 + l16;
    const float bv = bias[col];
    float sv = 0.f, qv = 0.f;
#pragma unroll
    for (int r = 0; r < 4; ++r) {
      const int row = orow0 + r;
      if (row < NN) {
        const float o = acc[n][r] + bv;
        outb[(size_t)row * DD + col] = f2bf(o);
        sv += o; qv += o * o;
      }
    }
    sv += __shfl_xor(sv, 16); qv += __shfl_xor(qv, 16);
    sv += __shfl_xor(sv, 32); qv += __shfl_xor(qv, 32);
    if (quad == 0) { atomicAdd(&bsum[col], sv); atomicAdd(&bsq[col], qv); }
  }
  __syncthreads();
  if (tid < DD) {
    const int rep = (blockIdx.x & (NREP - 1)) * DD;
    atomicAdd(&sum2r[rep + tid], bsum[tid]);
    atomicAdd(&sumsq2r[rep + tid], bsq[tid]);
  }
}

// K4: collapse BN2 replicas -> scale/shift in d_ws (replicas live in d_out,
// which k_bnrelu overwrites — must happen first).
__global__ void k_bnstats2(const float* __restrict__ sum2r,
                           const float* __restrict__ sumsq2r,
                           const float* __restrict__ gamma,
                           const float* __restrict__ beta,
                           float* __restrict__ scale,
                           float* __restrict__ shift) {
  const int c = threadIdx.x;
  float sm = 0.f, qm = 0.f;
#pragma unroll
  for (int r = 0; r < NREP; ++r) {
    sm += sum2r[r * DD + c];
    qm += sumsq2r[r * DD + c];
  }
  const float inv_n = 1.0f / (float)NN;
  const float mean = sm * inv_n;
  const float var = qm * inv_n - mean * mean;
  const float sc = gamma[c] * rsqrtf(var + BN_EPS);
  scale[c] = sc;
  shift[c] = beta[c] - mean * sc;
}

// K5: final BN2 + ReLU -> fp32 out
__global__ __launch_bounds__(256) void k_bnrelu(const unsigned short* __restrict__ in,
                                                const float* __restrict__ scale,
                                                const float* __restrict__ shift,
                                                float* __restrict__ out) {
  __shared__ float lsc[DD];
  __shared__ float lsh[DD];
  const int t = threadIdx.x;
  if (t < DD) {
    lsc[t] = scale[t];
    lsh[t] = shift[t];
  }
  __syncthreads();
  const int gid = blockIdx.x * 256 + t;
  const int c = (gid & 15) * 8;
  const u16x8 a = ((const u16x8*)in)[gid];
  const float4 sc0 = *(const float4*)&lsc[c];
  const float4 sc1 = *(const float4*)&lsc[c + 4];
  const float4 sh0 = *(const float4*)&lsh[c];
  const float4 sh1 = *(const float4*)&lsh[c + 4];
  float4 o0, o1;
  o0.x = fmaxf(fmaf(sc0.x, bf2f(a[0]), sh0.x), 0.f);
  o0.y = fmaxf(fmaf(sc0.y, bf2f(a[1]), sh0.y), 0.f);
  o0.z = fmaxf(fmaf(sc0.z, bf2f(a[2]), sh0.z), 0.f);
  o0.w = fmaxf(fmaf(sc0.w, bf2f(a[3]), sh0.w), 0.f);
  o1.x = fmaxf(fmaf(sc1.x, bf2f(a[4]), sh1.x), 0.f);
  o1.y = fmaxf(fmaf(sc1.y, bf2f(a[5]), sh1.y), 0.f);
  o1.z = fmaxf(fmaf(sc1.z, bf2f(a[6]), sh1.z), 0.f);
  o1.w = fmaxf(fmaf(sc1.w, bf2f(a[7]), sh1.w), 0.f);
  ((float4*)out)[gid * 2] = o0;
  ((float4*)out)[gid * 2 + 1] = o1;
}

// ---------------------------------------------------------------------------
extern "C" void kernel_launch(void* const* d_in, const int* in_sizes, int n_in,
                              void* d_out, int out_size, void* d_ws, size_t ws_size,
                              hipStream_t stream) {
  const float* x = (const float*)d_in[0];
  const int* ei = (const int*)d_in[1];
  const float* eps = (const float*)d_in[2];
  const float* W1 = (const float*)d_in[3];
  const float* b1 = (const float*)d_in[4];
  const float* g1 = (const float*)d_in[5];
  const float* be1 = (const float*)d_in[6];
  const float* W2 = (const float*)d_in[7];
  const float* b2 = (const float*)d_in[8];
  const float* g2 = (const float*)d_in[9];
  const float* be2 = (const float*)d_in[10];
  float* out = (float*)d_out;

  const int* rows = ei;
  const int* cols = ei + EE;

  // d_out scratch (dead before k_bnrelu writes d_out)
  int* bcur = (int*)d_out;                                  // NBUCK ints
  unsigned short* xb = (unsigned short*)d_out + 2000000;    // byte 4.0M
  unsigned int* bbuf = (unsigned int*)((char*)d_out + 16800000);  // 6.4MB
  unsigned short* W1b = (unsigned short*)d_out + 11640000;  // byte 23.28M
  unsigned short* W2b = (unsigned short*)d_out + 11680000;  // byte 23.36M
  float* reps = (float*)d_out + 5875000;                    // byte 23.5M, 64KB
  float* sum1r = reps;
  float* sumsq1r = reps + NREP * DD;
  float* sum2r = reps + 2 * NREP * DD;
  float* sumsq2r = reps + 3 * NREP * DD;

  unsigned short* h1b = (unsigned short*)d_ws;        // aggemm1 out
  unsigned short* h2b = h1b + (size_t)NN * DD;        // gemm2 out
  float* stats = (float*)(h1b + (size_t)2 * NN * DD); // 4KB tail of d_ws
  float* scale2 = stats + 0;
  float* shift2 = stats + 128;

  // 1. prep: x/W1/W2 -> bf16, zero bcur + stat replicas
  k_prep<<<XCONV_B + 32, 256, 0, stream>>>(x, W1, W2, xb, W1b, W2b, bcur, reps);
  // 2. bin edges into fixed 32-row buckets (packed u32)
  k_bin0<<<BIN_BLOCKS, 256, 0, stream>>>(rows, cols, bcur, bbuf);
  // 3. FUSED per-bucket sort + gather aggregation + GEMM1 -> h1b, BN1 stats
  k_aggemm1<<<NBUCK, 128, 0, stream>>>(xb, eps, bcur, bbuf, W1b, b1, h1b,
                                       sum1r, sumsq1r);
  // 4. GEMM2 (BN1+ReLU on the fly) -> h2b, BN2 stats
  k_gemm2<<<GEMM_B, 256, 0, stream>>>(h1b, sum1r, sumsq1r, g1, be1, W2b, b2,
                                      h2b, sum2r, sumsq2r);
  // 5. collapse BN2 replicas into d_ws
  k_bnstats2<<<1, 128, 0, stream>>>(sum2r, sumsq2r, g2, be2, scale2, shift2);
  // 6. final BN2+ReLU -> fp32 out
  k_bnrelu<<<(NN * DD / 8) / 256, 256, 0, stream>>>(h2b, scale2, shift2, out);
}